// Round 14
// baseline (361.113 us; speedup 1.0000x reference)
//
#include <hip/hip_runtime.h>
#include <cstdint>
#include <cstddef>

#define NN 100000
#define NE 1600000
#define DIM 256
#define NA 100352            // NN rounded up
#define PAD 16               // one counter per 64B line

// int-offset layout in ws (sequential carve):
//  outd_pad[NA*PAD] | ind_pad[NA*PAD] | rowp[NA+16] | bsum[512]
//  | normsrc[NA] f32 | normdst[NA] f32 | csr[NE]
//  then bf16: hs[NN*DIM] | wtp[DIM*DIM]; then rank[NE] ints
#define OUTD_I  0
#define IND_I   (NA*PAD)
#define ROWP_I  (2*NA*PAD)
#define BSUM_I  (ROWP_I + NA + 16)
#define NSRC_I  (BSUM_I + 512)
#define NDST_I  (NSRC_I + NA)
#define CSR_I   (NDST_I + NA)
#define HS_B    ((size_t)(CSR_I + NE) * 4)
#define WT_B    (HS_B + (size_t)NN*DIM*2)
#define RANK_B  (WT_B + (size_t)DIM*DIM*2)
#define WS_NEED (RANK_B + (size_t)NE*4)

typedef short bf16x8 __attribute__((ext_vector_type(8)));
typedef float f32x4 __attribute__((ext_vector_type(4)));
typedef unsigned short u16x4 __attribute__((ext_vector_type(4)));

__device__ __forceinline__ float bf2f(unsigned short u) {
    return __uint_as_float(((unsigned)u) << 16);
}
__device__ __forceinline__ unsigned short f2bf(float f) {
    unsigned u = __float_as_uint(f);
    u += 0x7FFF + ((u >> 16) & 1);   // round-to-nearest-even
    return (unsigned short)(u >> 16);
}

// ---- fused: degree histograms (line-padded) + slot ranks + h->bf16 ---------
__global__ __launch_bounds__(256) void k_count_conv(
        const int* __restrict__ src, const int* __restrict__ dst,
        const float* __restrict__ h,
        int* __restrict__ outd, int* __restrict__ ind,
        int* __restrict__ rank, unsigned short* __restrict__ hs) {
    int gid = blockIdx.x * blockDim.x + threadIdx.x;
    int gstride = gridDim.x * blockDim.x;
    for (int e = gid; e < NE; e += gstride) {
        atomicAdd(&outd[src[e] * PAD], 1);
        rank[e] = atomicAdd(&ind[dst[e] * PAD], 1);
    }
    for (int i = gid; i < NN * (DIM / 4); i += gstride) {
        float4 v = ((const float4*)h)[i];
        u16x4 o;
        o.x = f2bf(v.x);
        o.y = f2bf(v.y);
        o.z = f2bf(v.z);
        o.w = f2bf(v.w);
        ((u16x4*)hs)[i] = o;
    }
}

// ---- 3-kernel exclusive prefix scan of padded in_deg -> row_ptr ------------
#define SCAN_NB 98   // ceil(NN/1024)

__global__ void k_scan1(const int* __restrict__ ind, int* __restrict__ rowp,
                        int* __restrict__ bsum) {
    __shared__ int tmp[1024];
    int t = threadIdx.x;
    int i = blockIdx.x * 1024 + t;
    int x = (i < NN) ? ind[i * PAD] : 0;
    tmp[t] = x;
    __syncthreads();
    for (int off = 1; off < 1024; off <<= 1) {
        int v = (t >= off) ? tmp[t - off] : 0;
        __syncthreads();
        tmp[t] += v;
        __syncthreads();
    }
    if (i < NN) rowp[i] = tmp[t] - x;           // exclusive within block
    if (t == 1023) bsum[blockIdx.x] = tmp[t];   // block total
}

__global__ void k_scan2(int* __restrict__ bsum) {
    __shared__ int tmp[128];
    int t = threadIdx.x;
    int x = (t < SCAN_NB) ? bsum[t] : 0;
    tmp[t] = x;
    __syncthreads();
    for (int off = 1; off < 128; off <<= 1) {
        int v = (t >= off) ? tmp[t - off] : 0;
        __syncthreads();
        tmp[t] += v;
        __syncthreads();
    }
    if (t < SCAN_NB) bsum[t] = tmp[t] - x;      // exclusive
}

// finalize rowp; emit normsrc/normdst compact f32 tables
__global__ void k_scan3(int* __restrict__ rowp, const int* __restrict__ bsum,
                        const int* __restrict__ outd, const int* __restrict__ ind,
                        float* __restrict__ normsrc, float* __restrict__ normdst) {
    int i = blockIdx.x * 1024 + threadIdx.x;
    if (i < NN) {
        rowp[i] += bsum[blockIdx.x];
        normsrc[i] = rsqrtf(fmaxf((float)outd[i * PAD], 1.0f));
        normdst[i] = rsqrtf(fmaxf((float)ind[i * PAD], 1.0f));
    }
    if (i == 0) rowp[NN] = NE;
}

// ---- streaming finish: CSR scatter (no atomics) + weight pack --------------
__global__ __launch_bounds__(256) void k_scatter(
        const int* __restrict__ src, const int* __restrict__ dst,
        const int* __restrict__ rank, const int* __restrict__ rowp,
        const float* __restrict__ W,
        int* __restrict__ csr, unsigned short* __restrict__ wtp) {
    int gid = blockIdx.x * blockDim.x + threadIdx.x;
    int gstride = gridDim.x * blockDim.x;
    for (int p = gid; p < DIM * DIM; p += gstride) {
        int j = p & 7, l = (p >> 3) & 63, t = (p >> 9) & 15, ks = p >> 13;
        wtp[p] = f2bf(W[(ks * 32 + (l >> 4) * 8 + j) * DIM + t * 16 + (l & 15)]);
    }
    for (int e = gid; e < NE; e += gstride) {
        csr[rowp[dst[e]] + rank[e]] = src[e];
    }
}

// ---- FUSED aggregate + GEMM + bias + ELU (R13-passing, normdst table) ------
__global__ __launch_bounds__(256) void k_aggemm(const unsigned short* __restrict__ hs,
                                                const int* __restrict__ csr,
                                                const int* __restrict__ rowp,
                                                const float* __restrict__ normdst,
                                                const float* __restrict__ normsrc,
                                                const unsigned short* __restrict__ wtp,
                                                const float* __restrict__ bias,
                                                float* __restrict__ out) {
    __shared__ short As[16][264];
    int wave = threadIdx.x >> 6;
    int lane = threadIdx.x & 63;
    int nb = blockIdx.x * 16;

    // ---- phase 1: aggregate 4 nodes per wave ----
    for (int i = 0; i < 4; ++i) {
        int r = wave * 4 + i;
        int node = nb + r;
        int e0 = rowp[node], e1 = rowp[node + 1];
        float a0 = 0.f, a1 = 0.f, a2 = 0.f, a3 = 0.f;
        for (int base = e0; base < e1; base += 64) {
            int n = e1 - base;
            if (n > 64) n = 64;
            int idx = base + lane;
            int csrv = (idx < e1) ? csr[idx] : 0;
            int j = 0;
            for (; j + 3 < n; j += 4) {
                int s0 = __builtin_amdgcn_readlane(csrv, j);
                int s1 = __builtin_amdgcn_readlane(csrv, j + 1);
                int s2 = __builtin_amdgcn_readlane(csrv, j + 2);
                int s3 = __builtin_amdgcn_readlane(csrv, j + 3);
                float n0 = normsrc[s0], n1 = normsrc[s1];
                float n2 = normsrc[s2], n3 = normsrc[s3];
                u16x4 u0 = ((const u16x4*)(hs + (size_t)s0 * DIM))[lane];
                u16x4 u1 = ((const u16x4*)(hs + (size_t)s1 * DIM))[lane];
                u16x4 u2 = ((const u16x4*)(hs + (size_t)s2 * DIM))[lane];
                u16x4 u3 = ((const u16x4*)(hs + (size_t)s3 * DIM))[lane];
                a0 = fmaf(bf2f(u0.x), n0, fmaf(bf2f(u1.x), n1,
                     fmaf(bf2f(u2.x), n2, fmaf(bf2f(u3.x), n3, a0))));
                a1 = fmaf(bf2f(u0.y), n0, fmaf(bf2f(u1.y), n1,
                     fmaf(bf2f(u2.y), n2, fmaf(bf2f(u3.y), n3, a1))));
                a2 = fmaf(bf2f(u0.z), n0, fmaf(bf2f(u1.z), n1,
                     fmaf(bf2f(u2.z), n2, fmaf(bf2f(u3.z), n3, a2))));
                a3 = fmaf(bf2f(u0.w), n0, fmaf(bf2f(u1.w), n1,
                     fmaf(bf2f(u2.w), n2, fmaf(bf2f(u3.w), n3, a3))));
            }
            for (; j < n; ++j) {
                int s0 = __builtin_amdgcn_readlane(csrv, j);
                float n0 = normsrc[s0];
                u16x4 u = ((const u16x4*)(hs + (size_t)s0 * DIM))[lane];
                a0 = fmaf(bf2f(u.x), n0, a0);
                a1 = fmaf(bf2f(u.y), n0, a1);
                a2 = fmaf(bf2f(u.z), n0, a2);
                a3 = fmaf(bf2f(u.w), n0, a3);
            }
        }
        float nd = normdst[node];
        u16x4 o;
        o.x = f2bf(a0 * nd);
        o.y = f2bf(a1 * nd);
        o.z = f2bf(a2 * nd);
        o.w = f2bf(a3 * nd);
        *(u16x4*)&As[r][4 * lane] = o;   // linear across lanes: conflict-free
    }
    __syncthreads();

    // ---- phase 2: 16x256 GEMM quadrant per wave ----
    const short* B = (const short*)wtp + lane * 8;
    f32x4 acc[4];
#pragma unroll
    for (int tt = 0; tt < 4; ++tt) acc[tt] = (f32x4){0.f, 0.f, 0.f, 0.f};

    int fr = lane & 15;      // A-row / C-col fragment index
    int q  = lane >> 4;      // k-group / C-row group
    for (int ks = 0; ks < 8; ++ks) {
        bf16x8 a = *(const bf16x8*)&As[fr][ks * 32 + q * 8];
#pragma unroll
        for (int tt = 0; tt < 4; ++tt) {
            int t = wave * 4 + tt;
            bf16x8 b = *(const bf16x8*)(B + (size_t)(ks * 16 + t) * 512);
            acc[tt] = __builtin_amdgcn_mfma_f32_16x16x32_bf16(a, b, acc[tt], 0, 0, 0);
        }
    }

    // ---- epilogue: bias + ELU + store ----
    int rbase = nb + q * 4;
#pragma unroll
    for (int tt = 0; tt < 4; ++tt) {
        int col = wave * 64 + tt * 16 + fr;
        float bv = bias[col];
#pragma unroll
        for (int i = 0; i < 4; ++i) {
            float v = acc[tt][i] + bv;
            v = v > 0.f ? v : expm1f(v);
            __builtin_nontemporal_store(v, &out[(size_t)(rbase + i) * DIM + col]);
        }
    }
}

extern "C" void kernel_launch(void* const* d_in, const int* in_sizes, int n_in,
                              void* d_out, int out_size, void* d_ws, size_t ws_size,
                              hipStream_t stream) {
    const float* h    = (const float*)d_in[0];
    const float* W    = (const float*)d_in[1];
    const float* bias = (const float*)d_in[2];
    const int*   src  = (const int*)d_in[3];
    const int*   dst  = (const int*)d_in[4];
    float* out = (float*)d_out;

    if (ws_size < WS_NEED) return;  // insufficient scratch -> loud failure

    char* w = (char*)d_ws;
    int* base = (int*)w;
    int* outd = base + OUTD_I;
    int* ind  = base + IND_I;
    int* rowp = base + ROWP_I;
    int* bsum = base + BSUM_I;
    float* normsrc = (float*)(base + NSRC_I);
    float* normdst = (float*)(base + NDST_I);
    int* csr  = base + CSR_I;
    unsigned short* hs  = (unsigned short*)(w + HS_B);
    unsigned short* wtp = (unsigned short*)(w + WT_B);
    int* rank = (int*)(w + RANK_B);

    // zero both padded histograms (contiguous 2*NA*PAD ints = 12.85 MB)
    hipMemsetAsync(outd, 0, (size_t)2 * NA * PAD * sizeof(int), stream);

    k_count_conv<<<2048, 256, 0, stream>>>(src, dst, h, outd, ind, rank, hs);
    k_scan1<<<SCAN_NB, 1024, 0, stream>>>(ind, rowp, bsum);
    k_scan2<<<1, 128, 0, stream>>>(bsum);
    k_scan3<<<SCAN_NB, 1024, 0, stream>>>(rowp, bsum, outd, ind, normsrc, normdst);
    k_scatter<<<2048, 256, 0, stream>>>(src, dst, rank, rowp, W, csr, wtp);
    k_aggemm<<<NN / 16, 256, 0, stream>>>(hs, csr, rowp, normdst, normsrc, wtp, bias, out);
}